// Round 1
// baseline (436.115 us; speedup 1.0000x reference)
//
#include <hip/hip_runtime.h>
#include <hip/hip_bf16.h>

// Shapes: B=1024, C=80, D_WORD=300, J=8000, IMG_CH=2048
// Factorization: out = feature @ H^T + r, H = cls_proj @ W_img, r = cls_proj @ b_img
// cls_proj = x2 @ W_cls^T + b_cls;  x2 = adj @ (leaky(adj @ (inp0@W_gc1)) @ W_gc2)

typedef __bf16 bf16_t;
typedef __bf16 bf16x8 __attribute__((ext_vector_type(8)));
typedef float f32x4 __attribute__((ext_vector_type(4)));

#define MFMA16(a, b, c) __builtin_amdgcn_mfma_f32_16x16x32_bf16((a), (b), (c), 0, 0, 0)

__device__ inline bf16x8 cvt8(float4 a, float4 b) {
  bf16x8 v;
  v[0] = (bf16_t)a.x; v[1] = (bf16_t)a.y; v[2] = (bf16_t)a.z; v[3] = (bf16_t)a.w;
  v[4] = (bf16_t)b.x; v[5] = (bf16_t)b.y; v[6] = (bf16_t)b.z; v[7] = (bf16_t)b.w;
  return v;
}

// ---- adj[i][j] = D[i]*D[j]*A[j][i], D = rsqrt(rowsum(A)) ----
__global__ void k_adj(const float* __restrict__ A, float* __restrict__ adj) {
  __shared__ float Dv[80];
  int tid = threadIdx.x;
  if (tid < 80) {
    float s = 0.f;
    #pragma unroll 4
    for (int j = 0; j < 80; ++j) s += A[tid * 80 + j];
    Dv[tid] = rsqrtf(s);
  }
  __syncthreads();
  for (int idx = tid; idx < 6400; idx += blockDim.x) {
    int i = idx / 80, j = idx % 80;
    adj[idx] = Dv[i] * Dv[j] * A[j * 80 + i];
  }
}

// ---- t1 = inp0 @ W_gc1 : [80,1024], K=300 ----
__global__ void k_gc1(const float* __restrict__ inp0, const float* __restrict__ Wgc1,
                      float* __restrict__ t1) {
  int idx = blockIdx.x * blockDim.x + threadIdx.x;  // 81920
  int c = idx >> 10, n = idx & 1023;
  const float* ir = inp0 + c * 300;
  float acc = 0.f;
  #pragma unroll 4
  for (int k = 0; k < 300; ++k) acc += ir[k] * Wgc1[k * 1024 + n];
  t1[idx] = acc;
}

// ---- x1 = leaky_relu(adj @ t1, 0.2) : [80,1024] ----
__global__ void k_adjmul_leaky(const float* __restrict__ adj, const float* __restrict__ t1,
                               float* __restrict__ x1) {
  int idx = blockIdx.x * blockDim.x + threadIdx.x;  // 81920
  int c = idx >> 10, n = idx & 1023;
  const float* ar = adj + c * 80;
  float acc = 0.f;
  #pragma unroll 4
  for (int cc = 0; cc < 80; ++cc) acc += ar[cc] * t1[cc * 1024 + n];
  x1[idx] = acc > 0.f ? acc : 0.2f * acc;
}

// ---- t2 = x1 @ W_gc2 : [80,2048], K=1024 ----
__global__ void k_gc2(const float* __restrict__ x1, const float* __restrict__ Wgc2,
                      float* __restrict__ t2) {
  int idx = blockIdx.x * blockDim.x + threadIdx.x;  // 163840
  int c = idx >> 11, n = idx & 2047;
  const float* xr = x1 + c * 1024;
  float acc = 0.f;
  #pragma unroll 4
  for (int k = 0; k < 1024; ++k) acc += xr[k] * Wgc2[k * 2048 + n];
  t2[idx] = acc;
}

// ---- x2 = bf16(adj @ t2) : [80,2048] ----
__global__ void k_adjmul_bf16(const float* __restrict__ adj, const float* __restrict__ t2,
                              bf16_t* __restrict__ x2) {
  int idx = blockIdx.x * blockDim.x + threadIdx.x;  // 163840
  int c = idx >> 11, n = idx & 2047;
  const float* ar = adj + c * 80;
  float acc = 0.f;
  #pragma unroll 4
  for (int cc = 0; cc < 80; ++cc) acc += ar[cc] * t2[cc * 2048 + n];
  x2[idx] = (bf16_t)acc;
}

// ---- P = bf16(x2 @ W_cls^T + b_cls) : [80,8000];  r[c] += b_img . P[c,:] ----
// grid 500 (j-tiles of 16), 256 threads = 4 waves splitting K=2048 into 4x512
__global__ __launch_bounds__(256) void k_clsproj(
    const float* __restrict__ Wcls, const float* __restrict__ bcls,
    const float* __restrict__ bimg, const bf16_t* __restrict__ x2,
    bf16_t* __restrict__ P, float* __restrict__ r) {
  int tid = threadIdx.x;
  int w = tid >> 6, l = tid & 63;
  int ln = l & 15, q = l >> 4;
  int j0 = blockIdx.x * 16;
  size_t jrow = (size_t)(j0 + ln) * 2048;

  __shared__ float red[4][80][16];
  __shared__ float rloc[80];
  if (tid < 80) rloc[tid] = 0.f;

  f32x4 acc[5] = {};
  int kbase = w * 512 + q * 8;
  for (int ks = 0; ks < 16; ++ks) {
    int kq = kbase + ks * 32;
    const float4* bp = (const float4*)(Wcls + jrow + kq);
    float4 b0 = bp[0], b1 = bp[1];
    bf16x8 bfrag = cvt8(b0, b1);
    #pragma unroll
    for (int mt = 0; mt < 5; ++mt) {
      bf16x8 afrag = *(const bf16x8*)(x2 + (size_t)(mt * 16 + ln) * 2048 + kq);
      acc[mt] = MFMA16(afrag, bfrag, acc[mt]);
    }
  }
  #pragma unroll
  for (int mt = 0; mt < 5; ++mt)
    #pragma unroll
    for (int reg = 0; reg < 4; ++reg)
      red[w][mt * 16 + q * 4 + reg][ln] = acc[mt][reg];
  __syncthreads();

  for (int o = tid; o < 1280; o += 256) {
    int c = o >> 4, jj = o & 15;
    float v = red[0][c][jj] + red[1][c][jj] + red[2][c][jj] + red[3][c][jj] + bcls[j0 + jj];
    P[(size_t)c * 8000 + j0 + jj] = (bf16_t)v;
    atomicAdd(&rloc[c], bimg[j0 + jj] * v);
  }
  __syncthreads();
  if (tid < 80) atomicAdd(&r[tid], rloc[tid]);
}

// ---- H[c][n] += sum_j P[c][j]*W_img[j][n]  (fp32 atomics into zeroed H) ----
// grid 320 = 32 n-chunks(64) x 10 j-chunks(800); 4 waves: wave w -> n-tile nc*64+w*16
__global__ __launch_bounds__(256) void k_hmat(
    const float* __restrict__ Wimg, const bf16_t* __restrict__ P, float* __restrict__ H) {
  int tid = threadIdx.x;
  int w = tid >> 6, l = tid & 63;
  int ln = l & 15, q = l >> 4;
  int nc = blockIdx.x & 31, jc = blockIdx.x >> 5;
  int col = nc * 64 + w * 16 + ln;

  f32x4 acc[5] = {};
  int jbase = jc * 800 + q * 8;
  for (int ks = 0; ks < 25; ++ks) {
    int jq = jbase + ks * 32;
    const float* bp = Wimg + (size_t)jq * 2048 + col;
    bf16x8 bfrag;
    #pragma unroll
    for (int jj = 0; jj < 8; ++jj) bfrag[jj] = (bf16_t)bp[(size_t)jj * 2048];
    #pragma unroll
    for (int mt = 0; mt < 5; ++mt) {
      bf16x8 afrag = *(const bf16x8*)(P + (size_t)(mt * 16 + ln) * 8000 + jq);
      acc[mt] = MFMA16(afrag, bfrag, acc[mt]);
    }
  }
  #pragma unroll
  for (int mt = 0; mt < 5; ++mt)
    #pragma unroll
    for (int reg = 0; reg < 4; ++reg)
      atomicAdd(&H[(size_t)(mt * 16 + q * 4 + reg) * 2048 + col], acc[mt][reg]);
}

// ---- out[b][c] += sum_k feature[b][k]*H[c][k]  (+ r[c] once) ----
// grid 128 = 16 m-groups(64) x 8 k-chunks(256); 4 waves: wave w -> m-tile mg*64+w*16
__global__ __launch_bounds__(256) void k_out(
    const float* __restrict__ feat, const float* __restrict__ H,
    const float* __restrict__ r, float* __restrict__ out) {
  int tid = threadIdx.x;
  int w = tid >> 6, l = tid & 63;
  int ln = l & 15, q = l >> 4;
  int mg = blockIdx.x & 15, kc = blockIdx.x >> 4;
  int m0 = mg * 64 + w * 16;
  size_t frow = (size_t)(m0 + ln) * 2048;

  f32x4 acc[5] = {};
  int kbase = kc * 256 + q * 8;
  for (int ks = 0; ks < 8; ++ks) {
    int kq = kbase + ks * 32;
    const float4* ap = (const float4*)(feat + frow + kq);
    bf16x8 afrag = cvt8(ap[0], ap[1]);
    #pragma unroll
    for (int nt = 0; nt < 5; ++nt) {
      const float4* hp = (const float4*)(H + (size_t)(nt * 16 + ln) * 2048 + kq);
      bf16x8 bfrag = cvt8(hp[0], hp[1]);
      acc[nt] = MFMA16(afrag, bfrag, acc[nt]);
    }
  }
  #pragma unroll
  for (int nt = 0; nt < 5; ++nt)
    #pragma unroll
    for (int reg = 0; reg < 4; ++reg) {
      int b = m0 + q * 4 + reg;
      int c = nt * 16 + ln;
      float v = acc[nt][reg];
      if (kc == 0) v += r[c];
      atomicAdd(&out[b * 80 + c], v);
    }
}

extern "C" void kernel_launch(void* const* d_in, const int* in_sizes, int n_in,
                              void* d_out, int out_size, void* d_ws, size_t ws_size,
                              hipStream_t stream) {
  const float* feature = (const float*)d_in[0];
  const float* inp     = (const float*)d_in[1];  // [1,80,300] -> inp0
  const float* A       = (const float*)d_in[2];
  const float* Wgc1    = (const float*)d_in[3];
  const float* Wgc2    = (const float*)d_in[4];
  const float* Wimg    = (const float*)d_in[5];
  const float* bimg    = (const float*)d_in[6];
  const float* Wcls    = (const float*)d_in[7];
  const float* bcls    = (const float*)d_in[8];
  float* out = (float*)d_out;

  char* ws = (char*)d_ws;
  float*  adj = (float*)(ws + 0);         //  80x80    fp32   25,600 B
  float*  t1  = (float*)(ws + 25600);     //  80x1024  fp32  327,680 B
  float*  x1  = (float*)(ws + 353280);    //  80x1024  fp32  327,680 B
  float*  t2  = (float*)(ws + 680960);    //  80x2048  fp32  655,360 B
  bf16_t* x2  = (bf16_t*)(ws + 1336320);  //  80x2048  bf16  327,680 B
  bf16_t* P   = (bf16_t*)(ws + 1664000);  //  80x8000  bf16 1,280,000 B
  float*  H   = (float*)(ws + 2944000);   //  80x2048  fp32  655,360 B
  float*  r   = (float*)(ws + 3599360);   //  80       fp32      320 B

  hipMemsetAsync(H, 0, 80 * 2048 * 4, stream);
  hipMemsetAsync(r, 0, 80 * 4, stream);
  hipMemsetAsync(out, 0, 1024 * 80 * 4, stream);

  k_adj<<<1, 128, 0, stream>>>(A, adj);
  k_gc1<<<320, 256, 0, stream>>>(inp, Wgc1, t1);
  k_adjmul_leaky<<<320, 256, 0, stream>>>(adj, t1, x1);
  k_gc2<<<640, 256, 0, stream>>>(x1, Wgc2, t2);
  k_adjmul_bf16<<<640, 256, 0, stream>>>(adj, t2, x2);
  k_clsproj<<<500, 256, 0, stream>>>(Wcls, bcls, bimg, x2, P, r);
  k_hmat<<<320, 256, 0, stream>>>(Wimg, P, H);
  k_out<<<128, 256, 0, stream>>>(feature, H, r, out);
}

// Round 3
// 289.928 us; speedup vs baseline: 1.5042x; 1.5042x over previous
//
#include <hip/hip_runtime.h>
#include <hip/hip_bf16.h>

// Shapes: B=1024, C=80, D_WORD=300 (pad 384), J=8000, IMG_CH=2048
// out = feature @ H^T + r;  H = P @ W_img;  r = P @ b_img
// P = x2 @ W_cls^T + b_cls; x2 = adj @ t2; t2 = x1 @ Wgc2; x1 = leaky(adj @ t1); t1 = x0 @ Wgc1

typedef __bf16 bf16_t;
typedef __bf16 bf16x8 __attribute__((ext_vector_type(8)));
typedef float f32x4 __attribute__((ext_vector_type(4)));

#define MFMA16(a, b, c) __builtin_amdgcn_mfma_f32_16x16x32_bf16((a), (b), (c), 0, 0, 0)

__device__ inline bf16x8 cvt8(float4 a, float4 b) {
  bf16x8 v;
  v[0] = (bf16_t)a.x; v[1] = (bf16_t)a.y; v[2] = (bf16_t)a.z; v[3] = (bf16_t)a.w;
  v[4] = (bf16_t)b.x; v[5] = (bf16_t)b.y; v[6] = (bf16_t)b.z; v[7] = (bf16_t)b.w;
  return v;
}

// ---- adj[i][j] = D[i]*D[j]*A[j][i], D = rsqrt(rowsum(A)) ---- (R1 verbatim)
__global__ void k_adj(const float* __restrict__ A, float* __restrict__ adj) {
  __shared__ float Dv[80];
  int tid = threadIdx.x;
  if (tid < 80) {
    float s = 0.f;
    #pragma unroll 4
    for (int j = 0; j < 80; ++j) s += A[tid * 80 + j];
    Dv[tid] = rsqrtf(s);
  }
  __syncthreads();
  for (int idx = tid; idx < 6400; idx += blockDim.x) {
    int i = idx / 80, j = idx % 80;
    adj[idx] = Dv[i] * Dv[j] * A[j * 80 + i];
  }
}

// ---- x0b[c][k] = bf16(inp0[c][k]) for k<300 else 0 : [80,384] ----
__global__ void k_cvt0(const float* __restrict__ inp0, bf16_t* __restrict__ x0b) {
  int idx = blockIdx.x * blockDim.x + threadIdx.x;  // 80*384 = 30720
  if (idx < 30720) {
    int c = idx / 384, k = idx % 384;
    x0b[idx] = (k < 300) ? (bf16_t)inp0[c * 300 + k] : (bf16_t)0.f;
  }
}

// ---- t1 = x0 @ Wgc1 : [80,1024], K=300 padded to 384 ----
// grid 64 (n-tiles of 16); 4 waves split K into 4x96 (3 steps); mirrors k_clsproj
__global__ __launch_bounds__(256) void k_gc1m(
    const bf16_t* __restrict__ x0b, const float* __restrict__ Wgc1,
    float* __restrict__ t1) {
  int tid = threadIdx.x;
  int w = tid >> 6, l = tid & 63;
  int ln = l & 15, q = l >> 4;
  int n0 = blockIdx.x * 16;

  __shared__ float red[4][80][16];
  f32x4 acc[5] = {};
  for (int ks = 0; ks < 3; ++ks) {
    int kq = w * 96 + ks * 32 + q * 8;
    bf16x8 bfrag;
    #pragma unroll
    for (int jj = 0; jj < 8; ++jj) {
      int k = kq + jj;
      int kc = k < 300 ? k : 299;          // clamped index: no OOB even if speculated
      float wv = Wgc1[kc * 1024 + n0 + ln];
      bfrag[jj] = (bf16_t)(k < 300 ? wv : 0.f);
    }
    #pragma unroll
    for (int mt = 0; mt < 5; ++mt) {
      bf16x8 afrag = *(const bf16x8*)(x0b + (size_t)(mt * 16 + ln) * 384 + kq);
      acc[mt] = MFMA16(afrag, bfrag, acc[mt]);
    }
  }
  #pragma unroll
  for (int mt = 0; mt < 5; ++mt)
    #pragma unroll
    for (int reg = 0; reg < 4; ++reg)
      red[w][mt * 16 + q * 4 + reg][ln] = acc[mt][reg];
  __syncthreads();
  for (int o = tid; o < 1280; o += 256) {
    int c = o >> 4, nn = o & 15;
    t1[c * 1024 + n0 + nn] = red[0][c][nn] + red[1][c][nn] + red[2][c][nn] + red[3][c][nn];
  }
}

// ---- x1b = bf16(leaky_relu(adj @ t1, 0.2)) : [80,1024] ----
__global__ void k_adjmul_leaky(const float* __restrict__ adj, const float* __restrict__ t1,
                               bf16_t* __restrict__ x1b) {
  int idx = blockIdx.x * blockDim.x + threadIdx.x;  // 81920
  int c = idx >> 10, n = idx & 1023;
  const float* ar = adj + c * 80;
  float acc = 0.f;
  #pragma unroll 4
  for (int cc = 0; cc < 80; ++cc) acc += ar[cc] * t1[cc * 1024 + n];
  x1b[idx] = (bf16_t)(acc > 0.f ? acc : 0.2f * acc);
}

// ---- t2 = x1 @ Wgc2 : [80,2048], K=1024 ----
// grid 128 (n-tiles of 16); 4 waves split K into 4x256 (8 steps); mirrors k_clsproj
__global__ __launch_bounds__(256) void k_gc2m(
    const bf16_t* __restrict__ x1b, const float* __restrict__ Wgc2,
    float* __restrict__ t2) {
  int tid = threadIdx.x;
  int w = tid >> 6, l = tid & 63;
  int ln = l & 15, q = l >> 4;
  int n0 = blockIdx.x * 16;

  __shared__ float red[4][80][16];
  f32x4 acc[5] = {};
  for (int ks = 0; ks < 8; ++ks) {
    int kq = w * 256 + ks * 32 + q * 8;
    const float* bp = Wgc2 + (size_t)kq * 2048 + n0 + ln;
    bf16x8 bfrag;
    #pragma unroll
    for (int jj = 0; jj < 8; ++jj) bfrag[jj] = (bf16_t)bp[(size_t)jj * 2048];
    #pragma unroll
    for (int mt = 0; mt < 5; ++mt) {
      bf16x8 afrag = *(const bf16x8*)(x1b + (size_t)(mt * 16 + ln) * 1024 + kq);
      acc[mt] = MFMA16(afrag, bfrag, acc[mt]);
    }
  }
  #pragma unroll
  for (int mt = 0; mt < 5; ++mt)
    #pragma unroll
    for (int reg = 0; reg < 4; ++reg)
      red[w][mt * 16 + q * 4 + reg][ln] = acc[mt][reg];
  __syncthreads();
  for (int o = tid; o < 1280; o += 256) {
    int c = o >> 4, nn = o & 15;
    t2[c * 2048 + n0 + nn] = red[0][c][nn] + red[1][c][nn] + red[2][c][nn] + red[3][c][nn];
  }
}

// ---- x2 = bf16(adj @ t2) : [80,2048] ---- (R1 verbatim)
__global__ void k_adjmul_bf16(const float* __restrict__ adj, const float* __restrict__ t2,
                              bf16_t* __restrict__ x2) {
  int idx = blockIdx.x * blockDim.x + threadIdx.x;  // 163840
  int c = idx >> 11, n = idx & 2047;
  const float* ar = adj + c * 80;
  float acc = 0.f;
  #pragma unroll 4
  for (int cc = 0; cc < 80; ++cc) acc += ar[cc] * t2[cc * 2048 + n];
  x2[idx] = (bf16_t)acc;
}

// ---- P = bf16(x2 @ W_cls^T + b_cls) : [80,8000]; r[c] += b_img . P[c,:] ---- (R1 verbatim)
__global__ __launch_bounds__(256) void k_clsproj(
    const float* __restrict__ Wcls, const float* __restrict__ bcls,
    const float* __restrict__ bimg, const bf16_t* __restrict__ x2,
    bf16_t* __restrict__ P, float* __restrict__ r) {
  int tid = threadIdx.x;
  int w = tid >> 6, l = tid & 63;
  int ln = l & 15, q = l >> 4;
  int j0 = blockIdx.x * 16;
  size_t jrow = (size_t)(j0 + ln) * 2048;

  __shared__ float red[4][80][16];
  __shared__ float rloc[80];
  if (tid < 80) rloc[tid] = 0.f;

  f32x4 acc[5] = {};
  int kbase = w * 512 + q * 8;
  for (int ks = 0; ks < 16; ++ks) {
    int kq = kbase + ks * 32;
    const float4* bp = (const float4*)(Wcls + jrow + kq);
    float4 b0 = bp[0], b1 = bp[1];
    bf16x8 bfrag = cvt8(b0, b1);
    #pragma unroll
    for (int mt = 0; mt < 5; ++mt) {
      bf16x8 afrag = *(const bf16x8*)(x2 + (size_t)(mt * 16 + ln) * 2048 + kq);
      acc[mt] = MFMA16(afrag, bfrag, acc[mt]);
    }
  }
  #pragma unroll
  for (int mt = 0; mt < 5; ++mt)
    #pragma unroll
    for (int reg = 0; reg < 4; ++reg)
      red[w][mt * 16 + q * 4 + reg][ln] = acc[mt][reg];
  __syncthreads();

  for (int o = tid; o < 1280; o += 256) {
    int c = o >> 4, jj = o & 15;
    float v = red[0][c][jj] + red[1][c][jj] + red[2][c][jj] + red[3][c][jj] + bcls[j0 + jj];
    P[(size_t)c * 8000 + j0 + jj] = (bf16_t)v;
    atomicAdd(&rloc[c], bimg[j0 + jj] * v);
  }
  __syncthreads();
  if (tid < 80) atomicAdd(&r[tid], rloc[tid]);
}

// ---- H[c][n] += sum_j P[c][j]*W_img[j][n]  (fp32 atomics into zeroed H) ---- (R1 verbatim)
// grid 320 = 32 n-chunks(64) x 10 j-chunks(800); 4 waves: wave w -> n-tile nc*64+w*16
__global__ __launch_bounds__(256) void k_hmat(
    const float* __restrict__ Wimg, const bf16_t* __restrict__ P, float* __restrict__ H) {
  int tid = threadIdx.x;
  int w = tid >> 6, l = tid & 63;
  int ln = l & 15, q = l >> 4;
  int nc = blockIdx.x & 31, jc = blockIdx.x >> 5;
  int col = nc * 64 + w * 16 + ln;

  f32x4 acc[5] = {};
  int jbase = jc * 800 + q * 8;
  for (int ks = 0; ks < 25; ++ks) {
    int jq = jbase + ks * 32;
    const float* bp = Wimg + (size_t)jq * 2048 + col;
    bf16x8 bfrag;
    #pragma unroll
    for (int jj = 0; jj < 8; ++jj) bfrag[jj] = (bf16_t)bp[(size_t)jj * 2048];
    #pragma unroll
    for (int mt = 0; mt < 5; ++mt) {
      bf16x8 afrag = *(const bf16x8*)(P + (size_t)(mt * 16 + ln) * 8000 + jq);
      acc[mt] = MFMA16(afrag, bfrag, acc[mt]);
    }
  }
  #pragma unroll
  for (int mt = 0; mt < 5; ++mt)
    #pragma unroll
    for (int reg = 0; reg < 4; ++reg)
      atomicAdd(&H[(size_t)(mt * 16 + q * 4 + reg) * 2048 + col], acc[mt][reg]);
}

// ---- out[b][c] += sum_k feature[b][k]*H[c][k]  (+ r[c] once) ---- (R1 verbatim)
// grid 128 = 16 m-groups(64) x 8 k-chunks(256); 4 waves: wave w -> m-tile mg*64+w*16
__global__ __launch_bounds__(256) void k_out(
    const float* __restrict__ feat, const float* __restrict__ H,
    const float* __restrict__ r, float* __restrict__ out) {
  int tid = threadIdx.x;
  int w = tid >> 6, l = tid & 63;
  int ln = l & 15, q = l >> 4;
  int mg = blockIdx.x & 15, kc = blockIdx.x >> 4;
  int m0 = mg * 64 + w * 16;
  size_t frow = (size_t)(m0 + ln) * 2048;

  f32x4 acc[5] = {};
  int kbase = kc * 256 + q * 8;
  for (int ks = 0; ks < 8; ++ks) {
    int kq = kbase + ks * 32;
    const float4* ap = (const float4*)(feat + frow + kq);
    bf16x8 afrag = cvt8(ap[0], ap[1]);
    #pragma unroll
    for (int nt = 0; nt < 5; ++nt) {
      const float4* hp = (const float4*)(H + (size_t)(nt * 16 + ln) * 2048 + kq);
      bf16x8 bfrag = cvt8(hp[0], hp[1]);
      acc[nt] = MFMA16(afrag, bfrag, acc[nt]);
    }
  }
  #pragma unroll
  for (int nt = 0; nt < 5; ++nt)
    #pragma unroll
    for (int reg = 0; reg < 4; ++reg) {
      int b = m0 + q * 4 + reg;
      int c = nt * 16 + ln;
      float v = acc[nt][reg];
      if (kc == 0) v += r[c];
      atomicAdd(&out[b * 80 + c], v);
    }
}

extern "C" void kernel_launch(void* const* d_in, const int* in_sizes, int n_in,
                              void* d_out, int out_size, void* d_ws, size_t ws_size,
                              hipStream_t stream) {
  const float* feature = (const float*)d_in[0];
  const float* inp     = (const float*)d_in[1];  // [1,80,300]
  const float* A       = (const float*)d_in[2];
  const float* Wgc1    = (const float*)d_in[3];
  const float* Wgc2    = (const float*)d_in[4];
  const float* Wimg    = (const float*)d_in[5];
  const float* bimg    = (const float*)d_in[6];
  const float* Wcls    = (const float*)d_in[7];
  const float* bcls    = (const float*)d_in[8];
  float* out = (float*)d_out;

  char* ws = (char*)d_ws;
  float*  adj = (float*)(ws + 0);         //  80x80    fp32     25,600
  float*  t1  = (float*)(ws + 25600);     //  80x1024  fp32    327,680
  bf16_t* x1b = (bf16_t*)(ws + 353280);   //  80x1024  bf16    163,840
  float*  t2  = (float*)(ws + 517120);    //  80x2048  fp32    655,360
  bf16_t* x2  = (bf16_t*)(ws + 1172480);  //  80x2048  bf16    327,680
  bf16_t* P   = (bf16_t*)(ws + 1500160);  //  80x8000  bf16  1,280,000
  float*  H   = (float*)(ws + 2780160);   //  80x2048  fp32    655,360
  float*  r   = (float*)(ws + 3435520);   //  80       fp32        320
  bf16_t* x0b = (bf16_t*)(ws + 3435840);  //  80x384   bf16     61,440

  hipMemsetAsync(H, 0, 80 * 2048 * 4, stream);
  hipMemsetAsync(r, 0, 80 * 4, stream);
  hipMemsetAsync(out, 0, 1024 * 80 * 4, stream);

  k_adj<<<1, 128, 0, stream>>>(A, adj);
  k_cvt0<<<120, 256, 0, stream>>>(inp, x0b);
  k_gc1m<<<64, 256, 0, stream>>>(x0b, Wgc1, t1);
  k_adjmul_leaky<<<320, 256, 0, stream>>>(adj, t1, x1b);
  k_gc2m<<<128, 256, 0, stream>>>(x1b, Wgc2, t2);
  k_adjmul_bf16<<<640, 256, 0, stream>>>(adj, t2, x2);
  k_clsproj<<<500, 256, 0, stream>>>(Wcls, bcls, bimg, x2, P, r);
  k_hmat<<<320, 256, 0, stream>>>(Wimg, P, H);
  k_out<<<128, 256, 0, stream>>>(feature, H, r, out);
}

// Round 4
// 282.048 us; speedup vs baseline: 1.5462x; 1.0279x over previous
//
#include <hip/hip_runtime.h>
#include <hip/hip_bf16.h>

// Shapes: B=1024, C=80, D_WORD=300 (pad 384), J=8000, IMG_CH=2048
// out = feature @ H^T + r;  H = P @ W_img;  r = P @ b_img
// P = x2 @ W_cls^T + b_cls; x2 = adj @ t2; t2 = x1 @ Wgc2; x1 = leaky(adj @ t1); t1 = x0 @ Wgc1

typedef __bf16 bf16_t;
typedef __bf16 bf16x8 __attribute__((ext_vector_type(8)));
typedef float f32x4 __attribute__((ext_vector_type(4)));

#define MFMA16(a, b, c) __builtin_amdgcn_mfma_f32_16x16x32_bf16((a), (b), (c), 0, 0, 0)

__device__ inline bf16x8 cvt8(float4 a, float4 b) {
  bf16x8 v;
  v[0] = (bf16_t)a.x; v[1] = (bf16_t)a.y; v[2] = (bf16_t)a.z; v[3] = (bf16_t)a.w;
  v[4] = (bf16_t)b.x; v[5] = (bf16_t)b.y; v[6] = (bf16_t)b.z; v[7] = (bf16_t)b.w;
  return v;
}

// ---- adj[i][j] = D[i]*D[j]*A[j][i], D = rsqrt(rowsum(A)) ---- (R3 verbatim)
__global__ void k_adj(const float* __restrict__ A, float* __restrict__ adj) {
  __shared__ float Dv[80];
  int tid = threadIdx.x;
  if (tid < 80) {
    float s = 0.f;
    #pragma unroll 4
    for (int j = 0; j < 80; ++j) s += A[tid * 80 + j];
    Dv[tid] = rsqrtf(s);
  }
  __syncthreads();
  for (int idx = tid; idx < 6400; idx += blockDim.x) {
    int i = idx / 80, j = idx % 80;
    adj[idx] = Dv[i] * Dv[j] * A[j * 80 + i];
  }
}

// ---- x0b[c][k] = bf16(inp0[c][k]) for k<300 else 0 : [80,384] ---- (R3 verbatim)
__global__ void k_cvt0(const float* __restrict__ inp0, bf16_t* __restrict__ x0b) {
  int idx = blockIdx.x * blockDim.x + threadIdx.x;  // 80*384 = 30720
  if (idx < 30720) {
    int c = idx / 384, k = idx % 384;
    x0b[idx] = (k < 300) ? (bf16_t)inp0[c * 300 + k] : (bf16_t)0.f;
  }
}

// ---- t1 = x0 @ Wgc1 : [80,1024], K=300 padded to 384 ---- (R3 verbatim)
__global__ __launch_bounds__(256) void k_gc1m(
    const bf16_t* __restrict__ x0b, const float* __restrict__ Wgc1,
    float* __restrict__ t1) {
  int tid = threadIdx.x;
  int w = tid >> 6, l = tid & 63;
  int ln = l & 15, q = l >> 4;
  int n0 = blockIdx.x * 16;

  __shared__ float red[4][80][16];
  f32x4 acc[5] = {};
  for (int ks = 0; ks < 3; ++ks) {
    int kq = w * 96 + ks * 32 + q * 8;
    bf16x8 bfrag;
    #pragma unroll
    for (int jj = 0; jj < 8; ++jj) {
      int k = kq + jj;
      int kc = k < 300 ? k : 299;
      float wv = Wgc1[kc * 1024 + n0 + ln];
      bfrag[jj] = (bf16_t)(k < 300 ? wv : 0.f);
    }
    #pragma unroll
    for (int mt = 0; mt < 5; ++mt) {
      bf16x8 afrag = *(const bf16x8*)(x0b + (size_t)(mt * 16 + ln) * 384 + kq);
      acc[mt] = MFMA16(afrag, bfrag, acc[mt]);
    }
  }
  #pragma unroll
  for (int mt = 0; mt < 5; ++mt)
    #pragma unroll
    for (int reg = 0; reg < 4; ++reg)
      red[w][mt * 16 + q * 4 + reg][ln] = acc[mt][reg];
  __syncthreads();
  for (int o = tid; o < 1280; o += 256) {
    int c = o >> 4, nn = o & 15;
    t1[c * 1024 + n0 + nn] = red[0][c][nn] + red[1][c][nn] + red[2][c][nn] + red[3][c][nn];
  }
}

// ---- x1b = bf16(leaky_relu(adj @ t1, 0.2)) : [80,1024] ---- (R3 verbatim)
__global__ void k_adjmul_leaky(const float* __restrict__ adj, const float* __restrict__ t1,
                               bf16_t* __restrict__ x1b) {
  int idx = blockIdx.x * blockDim.x + threadIdx.x;  // 81920
  int c = idx >> 10, n = idx & 1023;
  const float* ar = adj + c * 80;
  float acc = 0.f;
  #pragma unroll 4
  for (int cc = 0; cc < 80; ++cc) acc += ar[cc] * t1[cc * 1024 + n];
  x1b[idx] = (bf16_t)(acc > 0.f ? acc : 0.2f * acc);
}

// ---- t2 += x1 @ Wgc2 : [80,2048], K=1024; LDS-staged coalesced Wgc2 ----
// grid 512 = 32 n-chunks(64) x 16 k-chunks(64); 2 stages of 32k per block; atomics into zeroed t2
__global__ __launch_bounds__(256) void k_gc2m(
    const bf16_t* __restrict__ x1b, const float* __restrict__ Wgc2,
    float* __restrict__ t2) {
  int tid = threadIdx.x;
  int w = tid >> 6, l = tid & 63;
  int ln = l & 15, q = l >> 4;
  int nc = blockIdx.x & 31, kc = blockIdx.x >> 5;

  __shared__ float Bs[32][66];
  f32x4 acc[5] = {};
  for (int s = 0; s < 2; ++s) {
    int k0 = kc * 64 + s * 32;
    #pragma unroll
    for (int it = 0; it < 2; ++it) {
      int slot = tid + it * 256;          // 512 float4 slots = 32k x 64n
      int kr = slot >> 4, nq = slot & 15;
      const float4 v = *(const float4*)(Wgc2 + (size_t)(k0 + kr) * 2048 + nc * 64 + nq * 4);
      *(float4*)&Bs[kr][nq * 4] = v;
    }
    __syncthreads();
    bf16x8 bfrag;
    #pragma unroll
    for (int jj = 0; jj < 8; ++jj) bfrag[jj] = (bf16_t)Bs[q * 8 + jj][w * 16 + ln];
    #pragma unroll
    for (int mt = 0; mt < 5; ++mt) {
      bf16x8 afrag = *(const bf16x8*)(x1b + (size_t)(mt * 16 + ln) * 1024 + k0 + q * 8);
      acc[mt] = MFMA16(afrag, bfrag, acc[mt]);
    }
    __syncthreads();
  }
  #pragma unroll
  for (int mt = 0; mt < 5; ++mt)
    #pragma unroll
    for (int reg = 0; reg < 4; ++reg)
      atomicAdd(&t2[(size_t)(mt * 16 + q * 4 + reg) * 2048 + nc * 64 + w * 16 + ln],
                acc[mt][reg]);
}

// ---- x2 = bf16(adj @ t2) : [80,2048] ---- (R3 verbatim)
__global__ void k_adjmul_bf16(const float* __restrict__ adj, const float* __restrict__ t2,
                              bf16_t* __restrict__ x2) {
  int idx = blockIdx.x * blockDim.x + threadIdx.x;  // 163840
  int c = idx >> 11, n = idx & 2047;
  const float* ar = adj + c * 80;
  float acc = 0.f;
  #pragma unroll 4
  for (int cc = 0; cc < 80; ++cc) acc += ar[cc] * t2[cc * 2048 + n];
  x2[idx] = (bf16_t)acc;
}

// ---- P = bf16(x2 @ W_cls^T + b_cls) : [80,8000]; r[c] += b_img . P[c,:] ---- (R3 verbatim)
__global__ __launch_bounds__(256) void k_clsproj(
    const float* __restrict__ Wcls, const float* __restrict__ bcls,
    const float* __restrict__ bimg, const bf16_t* __restrict__ x2,
    bf16_t* __restrict__ P, float* __restrict__ r) {
  int tid = threadIdx.x;
  int w = tid >> 6, l = tid & 63;
  int ln = l & 15, q = l >> 4;
  int j0 = blockIdx.x * 16;
  size_t jrow = (size_t)(j0 + ln) * 2048;

  __shared__ float red[4][80][16];
  __shared__ float rloc[80];
  if (tid < 80) rloc[tid] = 0.f;

  f32x4 acc[5] = {};
  int kbase = w * 512 + q * 8;
  for (int ks = 0; ks < 16; ++ks) {
    int kq = kbase + ks * 32;
    const float4* bp = (const float4*)(Wcls + jrow + kq);
    float4 b0 = bp[0], b1 = bp[1];
    bf16x8 bfrag = cvt8(b0, b1);
    #pragma unroll
    for (int mt = 0; mt < 5; ++mt) {
      bf16x8 afrag = *(const bf16x8*)(x2 + (size_t)(mt * 16 + ln) * 2048 + kq);
      acc[mt] = MFMA16(afrag, bfrag, acc[mt]);
    }
  }
  #pragma unroll
  for (int mt = 0; mt < 5; ++mt)
    #pragma unroll
    for (int reg = 0; reg < 4; ++reg)
      red[w][mt * 16 + q * 4 + reg][ln] = acc[mt][reg];
  __syncthreads();

  for (int o = tid; o < 1280; o += 256) {
    int c = o >> 4, jj = o & 15;
    float v = red[0][c][jj] + red[1][c][jj] + red[2][c][jj] + red[3][c][jj] + bcls[j0 + jj];
    P[(size_t)c * 8000 + j0 + jj] = (bf16_t)v;
    atomicAdd(&rloc[c], bimg[j0 + jj] * v);
  }
  __syncthreads();
  if (tid < 80) atomicAdd(&r[tid], rloc[tid]);
}

// ---- H[c][n] += sum_j P[c][j]*W_img[j][n]; LDS-staged coalesced Wimg ----
// grid 800 = 32 n-chunks(64) x 25 j-chunks(320); 10 stages of 32j; atomics into zeroed H
__global__ __launch_bounds__(256) void k_hmat(
    const float* __restrict__ Wimg, const bf16_t* __restrict__ P, float* __restrict__ H) {
  int tid = threadIdx.x;
  int w = tid >> 6, l = tid & 63;
  int ln = l & 15, q = l >> 4;
  int nc = blockIdx.x & 31, jc = blockIdx.x >> 5;

  __shared__ float Bs[32][66];
  f32x4 acc[5] = {};
  for (int s = 0; s < 10; ++s) {
    int j0 = jc * 320 + s * 32;
    #pragma unroll
    for (int it = 0; it < 2; ++it) {
      int slot = tid + it * 256;          // 512 float4 slots = 32j x 64n
      int jr = slot >> 4, nq = slot & 15;
      const float4 v = *(const float4*)(Wimg + (size_t)(j0 + jr) * 2048 + nc * 64 + nq * 4);
      *(float4*)&Bs[jr][nq * 4] = v;
    }
    __syncthreads();
    bf16x8 bfrag;
    #pragma unroll
    for (int jj = 0; jj < 8; ++jj) bfrag[jj] = (bf16_t)Bs[q * 8 + jj][w * 16 + ln];
    #pragma unroll
    for (int mt = 0; mt < 5; ++mt) {
      bf16x8 afrag = *(const bf16x8*)(P + (size_t)(mt * 16 + ln) * 8000 + j0 + q * 8);
      acc[mt] = MFMA16(afrag, bfrag, acc[mt]);
    }
    __syncthreads();
  }
  #pragma unroll
  for (int mt = 0; mt < 5; ++mt)
    #pragma unroll
    for (int reg = 0; reg < 4; ++reg)
      atomicAdd(&H[(size_t)(mt * 16 + q * 4 + reg) * 2048 + nc * 64 + w * 16 + ln],
                acc[mt][reg]);
}

// ---- out[b][c] += sum_k feature[b][k]*H[c][k]  (+ r[c] once) ---- (R3 verbatim)
__global__ __launch_bounds__(256) void k_out(
    const float* __restrict__ feat, const float* __restrict__ H,
    const float* __restrict__ r, float* __restrict__ out) {
  int tid = threadIdx.x;
  int w = tid >> 6, l = tid & 63;
  int ln = l & 15, q = l >> 4;
  int mg = blockIdx.x & 15, kc = blockIdx.x >> 4;
  int m0 = mg * 64 + w * 16;
  size_t frow = (size_t)(m0 + ln) * 2048;

  f32x4 acc[5] = {};
  int kbase = kc * 256 + q * 8;
  for (int ks = 0; ks < 8; ++ks) {
    int kq = kbase + ks * 32;
    const float4* ap = (const float4*)(feat + frow + kq);
    bf16x8 afrag = cvt8(ap[0], ap[1]);
    #pragma unroll
    for (int nt = 0; nt < 5; ++nt) {
      const float4* hp = (const float4*)(H + (size_t)(nt * 16 + ln) * 2048 + kq);
      bf16x8 bfrag = cvt8(hp[0], hp[1]);
      acc[nt] = MFMA16(afrag, bfrag, acc[nt]);
    }
  }
  #pragma unroll
  for (int nt = 0; nt < 5; ++nt)
    #pragma unroll
    for (int reg = 0; reg < 4; ++reg) {
      int b = m0 + q * 4 + reg;
      int c = nt * 16 + ln;
      float v = acc[nt][reg];
      if (kc == 0) v += r[c];
      atomicAdd(&out[b * 80 + c], v);
    }
}

extern "C" void kernel_launch(void* const* d_in, const int* in_sizes, int n_in,
                              void* d_out, int out_size, void* d_ws, size_t ws_size,
                              hipStream_t stream) {
  const float* feature = (const float*)d_in[0];
  const float* inp     = (const float*)d_in[1];  // [1,80,300]
  const float* A       = (const float*)d_in[2];
  const float* Wgc1    = (const float*)d_in[3];
  const float* Wgc2    = (const float*)d_in[4];
  const float* Wimg    = (const float*)d_in[5];
  const float* bimg    = (const float*)d_in[6];
  const float* Wcls    = (const float*)d_in[7];
  const float* bcls    = (const float*)d_in[8];
  float* out = (float*)d_out;

  char* ws = (char*)d_ws;
  float*  adj = (float*)(ws + 0);         //  80x80    fp32     25,600
  float*  t1  = (float*)(ws + 25600);     //  80x1024  fp32    327,680
  bf16_t* x1b = (bf16_t*)(ws + 353280);   //  80x1024  bf16    163,840
  float*  t2  = (float*)(ws + 517120);    //  80x2048  fp32    655,360
  bf16_t* x2  = (bf16_t*)(ws + 1172480);  //  80x2048  bf16    327,680
  bf16_t* P   = (bf16_t*)(ws + 1500160);  //  80x8000  bf16  1,280,000
  float*  H   = (float*)(ws + 2780160);   //  80x2048  fp32    655,360
  float*  r   = (float*)(ws + 3435520);   //  80       fp32        320
  bf16_t* x0b = (bf16_t*)(ws + 3435840);  //  80x384   bf16     61,440

  hipMemsetAsync(t2, 0, 80 * 2048 * 4, stream);
  hipMemsetAsync(H, 0, 80 * 2048 * 4, stream);
  hipMemsetAsync(r, 0, 80 * 4, stream);
  hipMemsetAsync(out, 0, 1024 * 80 * 4, stream);

  k_adj<<<1, 128, 0, stream>>>(A, adj);
  k_cvt0<<<120, 256, 0, stream>>>(inp, x0b);
  k_gc1m<<<64, 256, 0, stream>>>(x0b, Wgc1, t1);
  k_adjmul_leaky<<<320, 256, 0, stream>>>(adj, t1, x1b);
  k_gc2m<<<512, 256, 0, stream>>>(x1b, Wgc2, t2);
  k_adjmul_bf16<<<640, 256, 0, stream>>>(adj, t2, x2);
  k_clsproj<<<500, 256, 0, stream>>>(Wcls, bcls, bimg, x2, P, r);
  k_hmat<<<800, 256, 0, stream>>>(Wimg, P, H);
  k_out<<<128, 256, 0, stream>>>(feature, H, r, out);
}